// Round 1
// baseline (186.278 us; speedup 1.0000x reference)
//
#include <hip/hip_runtime.h>
#include <cstdint>

namespace {

constexpr int kH = 48, kW = 48, kHW = kH * kW;   // 2304
constexpr int kC = 256;
constexpr int kB = 2;
constexpr int kNHead = 8;
constexpr int kDK = 32;
constexpr int kKK = 49;
constexpr int kPad = 3;
constexpr float kInvTemp = 0.17677669529663687f;  // 1/sqrt(32)

// ---------------------------------------------------------------------------
// 1x1-conv projection: Out[b,o,p] = sum_c W[o,c] * X[b,c,p]  (+ optional Res)
// Block: 256 threads = 256 output channels; TP pixels per block staged in LDS.
// ---------------------------------------------------------------------------
template <bool kRes, int TP>
__global__ __launch_bounds__(256) void proj_kernel(
    const float* __restrict__ X, const float* __restrict__ Wm,
    const float* __restrict__ Res, float* __restrict__ Out) {
  __shared__ float4 xs[kC][TP / 4];
  const int b = blockIdx.y;
  const int p0 = blockIdx.x * TP;
  const float* Xb = X + (size_t)b * kC * kHW + p0;
  for (int idx = threadIdx.x; idx < kC * (TP / 4); idx += 256) {
    const int c = idx / (TP / 4), p4 = idx % (TP / 4);
    xs[c][p4] = *reinterpret_cast<const float4*>(Xb + c * kHW + p4 * 4);
  }
  __syncthreads();
  const int o = threadIdx.x;
  const float4* Wrow = reinterpret_cast<const float4*>(Wm + (size_t)o * kC);
  float acc[TP];
#pragma unroll
  for (int p = 0; p < TP; ++p) acc[p] = 0.f;
  for (int c4 = 0; c4 < kC / 4; ++c4) {
    const float4 w = Wrow[c4];
#pragma unroll
    for (int j = 0; j < 4; ++j) {
      const float wj = (j == 0) ? w.x : (j == 1) ? w.y : (j == 2) ? w.z : w.w;
      const int c = c4 * 4 + j;
#pragma unroll
      for (int p4 = 0; p4 < TP / 4; ++p4) {
        const float4 xv = xs[c][p4];  // wave-uniform -> LDS broadcast
        acc[p4 * 4 + 0] += wj * xv.x;
        acc[p4 * 4 + 1] += wj * xv.y;
        acc[p4 * 4 + 2] += wj * xv.z;
        acc[p4 * 4 + 3] += wj * xv.w;
      }
    }
  }
  float* Ob = Out + (size_t)b * kC * kHW + (size_t)o * kHW + p0;
  if (kRes) {
    const float* Rb = Res + (size_t)b * kC * kHW + (size_t)o * kHW + p0;
#pragma unroll
    for (int p4 = 0; p4 < TP / 4; ++p4) {
      const float4 r = *reinterpret_cast<const float4*>(Rb + p4 * 4);
      float4 ov;
      ov.x = acc[p4 * 4 + 0] + r.x;
      ov.y = acc[p4 * 4 + 1] + r.y;
      ov.z = acc[p4 * 4 + 2] + r.z;
      ov.w = acc[p4 * 4 + 3] + r.w;
      *reinterpret_cast<float4*>(Ob + p4 * 4) = ov;
    }
  } else {
#pragma unroll
    for (int p4 = 0; p4 < TP / 4; ++p4) {
      float4 ov;
      ov.x = acc[p4 * 4 + 0];
      ov.y = acc[p4 * 4 + 1];
      ov.z = acc[p4 * 4 + 2];
      ov.w = acc[p4 * 4 + 3];
      *reinterpret_cast<float4*>(Ob + p4 * 4) = ov;
    }
  }
}

// ---------------------------------------------------------------------------
// Local 7x7 attention. One wave = one 8x8 pixel tile for one (b, head).
// Halo (14x14) of projected k,v staged in LDS, zero-filled out of bounds
// (zero scores DO participate in the softmax, matching the reference).
// ---------------------------------------------------------------------------
__global__ __launch_bounds__(64) void attn_kernel(
    const float* __restrict__ qp, const float* __restrict__ kp,
    const float* __restrict__ vp, float* __restrict__ att) {
  constexpr int kHalo = 14;           // 8 + 2*3
  constexpr int kHaloN = kHalo * kHalo;  // 196
  constexpr int kStride = 197;        // bank-spread padding
  __shared__ float ks[kDK][kStride];
  __shared__ float vs[kDK][kStride];

  const int tile = blockIdx.x;        // 36 tiles (6x6)
  const int bh = blockIdx.y;          // b*8 + head
  const int b = bh >> 3, head = bh & 7;
  const int by = tile / 6, bx = tile % 6;
  const int gy0 = by * 8 - kPad, gx0 = bx * 8 - kPad;
  const int tid = threadIdx.x;
  const size_t base = (size_t)b * kC * kHW + (size_t)head * kDK * kHW;

  for (int d = 0; d < kDK; ++d) {
    const float* kd = kp + base + (size_t)d * kHW;
    const float* vd = vp + base + (size_t)d * kHW;
    for (int p = tid; p < kHaloN; p += 64) {
      const int hy = p / kHalo, hx = p % kHalo;
      const int gy = gy0 + hy, gx = gx0 + hx;
      const bool ok = (gy >= 0) & (gy < kH) & (gx >= 0) & (gx < kW);
      const int gi = gy * kW + gx;
      ks[d][p] = ok ? kd[gi] : 0.f;
      vs[d][p] = ok ? vd[gi] : 0.f;
    }
  }
  __syncthreads();

  const int ty = tid >> 3, tx = tid & 7;
  const int gy = by * 8 + ty, gx = bx * 8 + tx;
  const int gi = gy * kW + gx;

  float q[kDK];
#pragma unroll
  for (int d = 0; d < kDK; ++d) q[d] = qp[base + (size_t)d * kHW + gi];

  float s[kKK];
#pragma unroll
  for (int ky = 0; ky < 7; ++ky) {
#pragma unroll
    for (int kx = 0; kx < 7; ++kx) {
      const int pp = (ty + ky) * kHalo + tx + kx;
      float a = 0.f;
#pragma unroll
      for (int d = 0; d < kDK; ++d) a += q[d] * ks[d][pp];
      s[ky * 7 + kx] = a * kInvTemp;
    }
  }

  float m = s[0];
#pragma unroll
  for (int k = 1; k < kKK; ++k) m = fmaxf(m, s[k]);
  float sum = 0.f;
#pragma unroll
  for (int k = 0; k < kKK; ++k) {
    s[k] = __expf(s[k] - m);
    sum += s[k];
  }
  const float inv = 1.f / sum;

  float o[kDK];
#pragma unroll
  for (int d = 0; d < kDK; ++d) o[d] = 0.f;
#pragma unroll
  for (int ky = 0; ky < 7; ++ky) {
#pragma unroll
    for (int kx = 0; kx < 7; ++kx) {
      const int pp = (ty + ky) * kHalo + tx + kx;
      const float w = s[ky * 7 + kx];
#pragma unroll
      for (int d = 0; d < kDK; ++d) o[d] += w * vs[d][pp];
    }
  }
#pragma unroll
  for (int d = 0; d < kDK; ++d) att[base + (size_t)d * kHW + gi] = o[d] * inv;
}

}  // namespace

extern "C" void kernel_launch(void* const* d_in, const int* in_sizes, int n_in,
                              void* d_out, int out_size, void* d_ws, size_t ws_size,
                              hipStream_t stream) {
  const float* q   = (const float*)d_in[0];
  const float* k   = (const float*)d_in[1];
  const float* v   = (const float*)d_in[2];
  const float* Wq  = (const float*)d_in[3];
  const float* Wk  = (const float*)d_in[4];
  const float* Wv  = (const float*)d_in[5];
  const float* Wfc = (const float*)d_in[6];
  // d_in[7]=kernel(7), d_in[8]=pad(3) — compile-time constants here.
  float* out = (float*)d_out;

  const size_t N = (size_t)kB * kC * kHW;  // 1,179,648 floats per tensor
  float* ws = (float*)d_ws;
  float* qp  = ws;
  float* kpj = ws + N;
  float* vpj = ws + 2 * N;
  float* att = ws + 3 * N;

  constexpr int TP = 16;
  const dim3 gp(kHW / TP, kB);  // (144, 2)
  proj_kernel<false, TP><<<gp, 256, 0, stream>>>(q, Wq, nullptr, qp);
  proj_kernel<false, TP><<<gp, 256, 0, stream>>>(k, Wk, nullptr, kpj);
  proj_kernel<false, TP><<<gp, 256, 0, stream>>>(v, Wv, nullptr, vpj);

  attn_kernel<<<dim3(36, kB * kNHead), 64, 0, stream>>>(qp, kpj, vpj, att);

  proj_kernel<true, TP><<<gp, 256, 0, stream>>>(att, Wfc, q, out);
}

// Round 2
// 87.895 us; speedup vs baseline: 2.1193x; 2.1193x over previous
//
#include <hip/hip_runtime.h>

typedef unsigned int u32;
typedef unsigned short u16;
typedef __attribute__((ext_vector_type(8))) short short8v;
typedef __attribute__((ext_vector_type(4))) float f32x4;

namespace {

constexpr int kH = 48, kW = 48, kHW = kH * kW;       // 2304
constexpr int kC = 256;
constexpr int kB = 2;
constexpr int kM = kB * kHW;                          // 4608 GEMM rows
constexpr int kPH = 54, kPW = 56, kPP = kPH * kPW;    // padded kv grid (3024)
constexpr float kInvTemp = 0.17677669529663687f;      // 1/sqrt(32)

constexpr size_t XT_BYTES = (size_t)kM * kC * 2;          // 2,359,296
constexpr size_t KPAD_BYTES = (size_t)16 * kPP * 32 * 2;  // 3,096,576

__device__ __forceinline__ u16 f2bf(float f) {
  u32 u = __builtin_bit_cast(u32, f);
  return (u16)((u + 0x7fffu + ((u >> 16) & 1u)) >> 16);
}
__device__ __forceinline__ u32 pack2(float lo, float hi) {
  return (u32)f2bf(lo) | ((u32)f2bf(hi) << 16);
}
#define UPLO(u) __builtin_bit_cast(float, (u32)((u) << 16))
#define UPHI(u) __builtin_bit_cast(float, (u32)((u) & 0xffff0000u))

// ---------------------------------------------------------------------------
// fp32 [b][c][p] -> bf16 [b][p][c]  (64x64 tiles via LDS)
// ---------------------------------------------------------------------------
__global__ __launch_bounds__(256) void tcvt_kernel(
    const float* __restrict__ q, const float* __restrict__ k,
    const float* __restrict__ v, u16* __restrict__ xq, u16* __restrict__ xk,
    u16* __restrict__ xv) {
  const int z = blockIdx.z, tz = z >> 1, b = z & 1;
  const float* src = (tz == 0) ? q : (tz == 1) ? k : v;
  u16* dst = (tz == 0) ? xq : (tz == 1) ? xk : xv;
  const int p0 = blockIdx.x * 64, c0 = blockIdx.y * 64;
  __shared__ float tile[64 * 68];
  const int t = threadIdx.x;
#pragma unroll
  for (int i = 0; i < 4; ++i) {
    const int c = (t >> 4) + i * 16, p4 = t & 15;
    const float4 val =
        *(const float4*)&src[(size_t)(b * kC + c0 + c) * kHW + p0 + p4 * 4];
    *(float4*)&tile[c * 68 + p4 * 4] = val;
  }
  __syncthreads();
  const int p = t >> 2, cg = t & 3;
#pragma unroll
  for (int i = 0; i < 4; ++i) {
    const int cb = cg * 4 + i * 16;
    uint2 w;
    w.x = pack2(tile[(cb + 0) * 68 + p], tile[(cb + 1) * 68 + p]);
    w.y = pack2(tile[(cb + 2) * 68 + p], tile[(cb + 3) * 68 + p]);
    *(uint2*)&dst[(size_t)(b * kHW + p0 + p) * kC + c0 + cb] = w;
  }
}

// ---------------------------------------------------------------------------
// MFMA GEMM: C[m][o] = sum_c A[m][c] * W[o][c];  m = b*2304 + pixel.
// A bf16 [4608][256] (K contiguous), W fp32 [256][256] (K contiguous).
// EPI 0: bf16 [m][o]      (q projection, [b][p][hd])
// EPI 1: bf16 padded kv   ([bh][54*56][32])
// EPI 2: fp32 [b][o][p] + residual
// ---------------------------------------------------------------------------
template <int EPI>
__global__ __launch_bounds__(256) void gemm_kernel(
    const u16* __restrict__ A, const float* __restrict__ Wm,
    const float* __restrict__ Res, void* __restrict__ OutV) {
  __shared__ __align__(16) u16 As[64 * 64];
  __shared__ __align__(16) u16 Bs[64 * 64];
  const int t = threadIdx.x;
  const int m0 = blockIdx.x * 64, n0 = blockIdx.y * 64;
  const int l = t & 63, w = t >> 6, wm = w >> 1, wn = w & 1;
  f32x4 acc[2][2] = {};

  for (int kt = 0; kt < 4; ++kt) {
    const int k0 = kt * 64;
    if (kt) __syncthreads();
#pragma unroll
    for (int j = 0; j < 2; ++j) {  // stage A: 512 x 16B
      const int task = t + j * 256;
      const int r = task >> 3, ch = task & 7;
      const uint4 val = *(const uint4*)&A[(size_t)(m0 + r) * kC + k0 + ch * 8];
      const int byteoff = (ch * 16) ^ ((r & 7) << 4);
      *(uint4*)&As[r * 64 + (byteoff >> 1)] = val;
    }
#pragma unroll
    for (int j = 0; j < 4; ++j) {  // stage B with fp32->bf16 cvt
      const int task = t + j * 256;
      const int r = task >> 4, f4 = task & 15;
      const float4 val =
          *(const float4*)&Wm[(size_t)(n0 + r) * kC + k0 + f4 * 4];
      uint2 pk;
      pk.x = pack2(val.x, val.y);
      pk.y = pack2(val.z, val.w);
      const int byteoff = (f4 * 8) ^ ((r & 7) << 4);
      *(uint2*)&Bs[r * 64 + (byteoff >> 1)] = pk;
    }
    __syncthreads();
#pragma unroll
    for (int ks = 0; ks < 2; ++ks) {
      const int bo = ks * 64 + ((l >> 4) << 4);  // byte offset of k-chunk
      short8v a[2], bf[2];
#pragma unroll
      for (int mf = 0; mf < 2; ++mf) {
        const int row = wm * 32 + mf * 16 + (l & 15);
        a[mf] = *(const short8v*)&As[row * 64 + ((bo ^ ((row & 7) << 4)) >> 1)];
      }
#pragma unroll
      for (int nf = 0; nf < 2; ++nf) {
        const int row = wn * 32 + nf * 16 + (l & 15);
        bf[nf] = *(const short8v*)&Bs[row * 64 + ((bo ^ ((row & 7) << 4)) >> 1)];
      }
#pragma unroll
      for (int mf = 0; mf < 2; ++mf)
#pragma unroll
        for (int nf = 0; nf < 2; ++nf)
          acc[mf][nf] = __builtin_amdgcn_mfma_f32_16x16x32_bf16(
              a[mf], bf[nf], acc[mf][nf], 0, 0, 0);
    }
  }

  const int bb = m0 / kHW;  // block never straddles b (2304 % 64 == 0)
#pragma unroll
  for (int mf = 0; mf < 2; ++mf)
#pragma unroll
    for (int nf = 0; nf < 2; ++nf)
#pragma unroll
      for (int i = 0; i < 4; ++i) {
        const int m = m0 + wm * 32 + mf * 16 + ((l >> 4) << 2) + i;
        const int o = n0 + wn * 32 + nf * 16 + (l & 15);
        const float val = acc[mf][nf][i];
        if (EPI == 0) {
          ((u16*)OutV)[(size_t)m * kC + o] = f2bf(val);
        } else if (EPI == 1) {
          const int p = m - bb * kHW;
          const int y = p / kW, x = p - y * kW;
          const size_t addr =
              ((size_t)(bb * 8 + (o >> 5)) * kPP + (y + 3) * kPW + (x + 3)) *
                  32 +
              (o & 31);
          ((u16*)OutV)[addr] = f2bf(val);
        } else {
          const int p = m - bb * kHW;
          const size_t addr = ((size_t)(bb * kC + o)) * kHW + p;
          ((float*)OutV)[addr] = val + Res[addr];
        }
      }
}

// ---------------------------------------------------------------------------
// Local 7x7 attention. Block = 256 thr (4 waves) = one (b,h) 8x8 tile.
// 4 lanes per pixel split the 49 neighbors (n % 4 == lane>>4).
// Halo read branch-free from zero-padded kv buffers.
// ---------------------------------------------------------------------------
#define DOT_U4(accv, r, qb)                                  \
  accv += UPLO(r.x) * qf[qb + 0] + UPHI(r.x) * qf[qb + 1];   \
  accv += UPLO(r.y) * qf[qb + 2] + UPHI(r.y) * qf[qb + 3];   \
  accv += UPLO(r.z) * qf[qb + 4] + UPHI(r.z) * qf[qb + 5];   \
  accv += UPLO(r.w) * qf[qb + 6] + UPHI(r.w) * qf[qb + 7];

#define PV_U4(e, r, ob)                                      \
  of[ob + 0] += e * UPLO(r.x); of[ob + 1] += e * UPHI(r.x);  \
  of[ob + 2] += e * UPLO(r.y); of[ob + 3] += e * UPHI(r.y);  \
  of[ob + 4] += e * UPLO(r.z); of[ob + 5] += e * UPHI(r.z);  \
  of[ob + 6] += e * UPLO(r.w); of[ob + 7] += e * UPHI(r.w);

__global__ __launch_bounds__(256) void attn2_kernel(
    const u16* __restrict__ qbf, const u16* __restrict__ kpad,
    const u16* __restrict__ vpad, u16* __restrict__ att) {
  __shared__ __align__(16) u16 ks_[196 * 40];
  __shared__ __align__(16) u16 vs_[196 * 40];
  const int t = threadIdx.x;
  const int tile = blockIdx.x, bh = blockIdx.y;
  const int byy = tile / 6, bxx = tile % 6;
  const int b = bh >> 3, h = bh & 7;
  const int l = t & 63, w = t >> 6;
  const int pi = w * 16 + (l & 15);
  const int ty = pi >> 3, tx = pi & 7;
  const int ng = l >> 4;
  const int gp = (byy * 8 + ty) * kW + (bxx * 8 + tx);

  // q: 64B per pixel (redundant x4 across lane groups, L1-hit)
  const size_t qbase = ((size_t)(b * kHW + gp)) * kC + h * 32;
  const uint4 q0 = *(const uint4*)&qbf[qbase + 0];
  const uint4 q1 = *(const uint4*)&qbf[qbase + 8];
  const uint4 q2 = *(const uint4*)&qbf[qbase + 16];
  const uint4 q3 = *(const uint4*)&qbf[qbase + 24];
  float qf[32];
#define QUNPK(v, base)                                    \
  qf[base + 0] = UPLO(v.x); qf[base + 1] = UPHI(v.x);     \
  qf[base + 2] = UPLO(v.y); qf[base + 3] = UPHI(v.y);     \
  qf[base + 4] = UPLO(v.z); qf[base + 5] = UPHI(v.z);     \
  qf[base + 6] = UPLO(v.w); qf[base + 7] = UPHI(v.w);
  QUNPK(q0, 0) QUNPK(q1, 8) QUNPK(q2, 16) QUNPK(q3, 24)

  // halo staging: 196 pixels x 64B x {k,v} = 1568 16B tasks
  const size_t kvbase = (size_t)bh * kPP * 32;
  for (int task = t; task < 1568; task += 256) {
    const int mat = task >= 784;
    const int rem = task - mat * 784;
    const int hp = rem >> 2, ch = rem & 3;
    const int hy = hp / 14, hx = hp - hy * 14;
    const size_t src =
        kvbase + ((size_t)((byy * 8 + hy) * kPW + (bxx * 8 + hx))) * 32 +
        ch * 8;
    const uint4 val = *(const uint4*)&(mat ? vpad : kpad)[src];
    u16* dst = mat ? vs_ : ks_;
    *(uint4*)&dst[hp * 40 + ch * 8] = val;
  }
  __syncthreads();

  float s[13];
  float pm = -1e30f;
#pragma unroll
  for (int nn = 0; nn < 13; ++nn) {
    const int n = nn * 4 + ng;
    float sc = -1e30f;
    if (n < 49) {
      const int ky = n / 7, kx = n - ky * 7;
      const int pp = (ty + ky) * 14 + (tx + kx);
      const u16* kr = &ks_[pp * 40];
      const uint4 r0 = *(const uint4*)&kr[0];
      const uint4 r1 = *(const uint4*)&kr[8];
      const uint4 r2 = *(const uint4*)&kr[16];
      const uint4 r3 = *(const uint4*)&kr[24];
      float d = 0.f;
      DOT_U4(d, r0, 0) DOT_U4(d, r1, 8) DOT_U4(d, r2, 16) DOT_U4(d, r3, 24)
      sc = d * kInvTemp;
    }
    s[nn] = sc;
    pm = fmaxf(pm, sc);
  }
  pm = fmaxf(pm, __shfl_xor(pm, 16));
  pm = fmaxf(pm, __shfl_xor(pm, 32));
  float zs = 0.f;
#pragma unroll
  for (int nn = 0; nn < 13; ++nn) {
    const float e = __expf(s[nn] - pm);  // masked lanes: exp(-huge) = 0
    s[nn] = e;
    zs += e;
  }
  zs += __shfl_xor(zs, 16);
  zs += __shfl_xor(zs, 32);
  const float rinv = 1.0f / zs;

  float of[32];
#pragma unroll
  for (int d = 0; d < 32; ++d) of[d] = 0.f;
#pragma unroll
  for (int nn = 0; nn < 13; ++nn) {
    const int n = nn * 4 + ng;
    if (n < 49) {
      const int ky = n / 7, kx = n - ky * 7;
      const int pp = (ty + ky) * 14 + (tx + kx);
      const u16* vr = &vs_[pp * 40];
      const uint4 r0 = *(const uint4*)&vr[0];
      const uint4 r1 = *(const uint4*)&vr[8];
      const uint4 r2 = *(const uint4*)&vr[16];
      const uint4 r3 = *(const uint4*)&vr[24];
      const float e = s[nn];
      PV_U4(e, r0, 0) PV_U4(e, r1, 8) PV_U4(e, r2, 16) PV_U4(e, r3, 24)
    }
  }
#pragma unroll
  for (int d = 0; d < 32; ++d) {
    of[d] += __shfl_xor(of[d], 16);
    of[d] += __shfl_xor(of[d], 32);
  }
  // lane writes its own 8-d segment (static-index selects, no scratch)
  float seg[8];
#pragma unroll
  for (int j = 0; j < 8; ++j) {
    const float a01 = (ng == 0) ? of[j] : of[8 + j];
    const float a23 = (ng == 2) ? of[16 + j] : of[24 + j];
    seg[j] = (ng < 2) ? a01 : a23;
  }
  uint4 out;
  out.x = pack2(seg[0] * rinv, seg[1] * rinv);
  out.y = pack2(seg[2] * rinv, seg[3] * rinv);
  out.z = pack2(seg[4] * rinv, seg[5] * rinv);
  out.w = pack2(seg[6] * rinv, seg[7] * rinv);
  *(uint4*)&att[((size_t)(b * kHW + gp)) * kC + h * 32 + ng * 8] = out;
}

}  // namespace

extern "C" void kernel_launch(void* const* d_in, const int* in_sizes, int n_in,
                              void* d_out, int out_size, void* d_ws,
                              size_t ws_size, hipStream_t stream) {
  const float* q = (const float*)d_in[0];
  const float* k = (const float*)d_in[1];
  const float* v = (const float*)d_in[2];
  const float* Wq = (const float*)d_in[3];
  const float* Wk = (const float*)d_in[4];
  const float* Wv = (const float*)d_in[5];
  const float* Wfc = (const float*)d_in[6];
  float* out = (float*)d_out;

  char* ws = (char*)d_ws;
  u16* xtq = (u16*)(ws);
  u16* xtk = (u16*)(ws + XT_BYTES);
  u16* xtv = (u16*)(ws + 2 * XT_BYTES);
  u16* kpad = (u16*)(ws + 3 * XT_BYTES);
  u16* vpad = (u16*)(ws + 3 * XT_BYTES + KPAD_BYTES);
  u16* qbf = (u16*)(ws + 3 * XT_BYTES + 2 * KPAD_BYTES);
  u16* att = xtq;  // xtq dead after q-GEMM; attn runs later in-stream

  hipMemsetAsync(kpad, 0, KPAD_BYTES, stream);
  hipMemsetAsync(vpad, 0, KPAD_BYTES, stream);

  tcvt_kernel<<<dim3(kHW / 64, kC / 64, 6), 256, 0, stream>>>(q, k, v, xtq,
                                                              xtk, xtv);

  const dim3 gg(kM / 64, kC / 64);
  gemm_kernel<0><<<gg, 256, 0, stream>>>(xtq, Wq, nullptr, qbf);
  gemm_kernel<1><<<gg, 256, 0, stream>>>(xtk, Wk, nullptr, kpad);
  gemm_kernel<1><<<gg, 256, 0, stream>>>(xtv, Wv, nullptr, vpad);

  attn2_kernel<<<dim3(36, 16), 256, 0, stream>>>(qbf, kpad, vpad, att);

  gemm_kernel<2><<<gg, 256, 0, stream>>>(att, Wfc, q, out);
}

// Round 3
// 62.721 us; speedup vs baseline: 2.9699x; 1.4014x over previous
//
#include <hip/hip_runtime.h>

typedef unsigned int u32;
typedef unsigned short u16;
typedef __attribute__((ext_vector_type(8))) short short8v;
typedef __attribute__((ext_vector_type(4))) float f32x4;

namespace {

constexpr int kH = 48, kW = 48, kHW = kH * kW;       // 2304
constexpr int kC = 256;
constexpr int kB = 2;
constexpr int kM = kB * kHW;                          // 4608 GEMM rows
constexpr int kPH = 54, kPW = 56, kPP = kPH * kPW;    // padded kv grid (3024)
constexpr float kInvTemp = 0.17677669529663687f;      // 1/sqrt(32)

constexpr size_t XT_BYTES = (size_t)kM * kC * 2;          // 2,359,296
constexpr size_t KPAD_BYTES = (size_t)16 * kPP * 32 * 2;  // 3,096,576
// pad zero region: kpad ++ vpad contiguous = 6,193,152 B = 387,072 uint4
constexpr int kZeroU4 = (int)(2 * KPAD_BYTES / 16);       // 387,072
constexpr int kZeroPerBlk = kZeroU4 / 864;                // 448 (exact)

__device__ __forceinline__ u16 f2bf(float f) {
  u32 u = __builtin_bit_cast(u32, f);
  return (u16)((u + 0x7fffu + ((u >> 16) & 1u)) >> 16);
}
__device__ __forceinline__ u32 pack2(float lo, float hi) {
  return (u32)f2bf(lo) | ((u32)f2bf(hi) << 16);
}
#define UPLO(u) __builtin_bit_cast(float, (u32)((u) << 16))
#define UPHI(u) __builtin_bit_cast(float, (u32)((u) & 0xffff0000u))

// ---------------------------------------------------------------------------
// fp32 [b][c][p] -> bf16 [b][p][c]  (64x64 tiles via LDS)
// Also zeroes the padded kv buffers (replaces two 43us rocclr fills).
// ---------------------------------------------------------------------------
__global__ __launch_bounds__(256) void tcvt_kernel(
    const float* __restrict__ q, const float* __restrict__ k,
    const float* __restrict__ v, u16* __restrict__ xq, u16* __restrict__ xk,
    u16* __restrict__ xv, uint4* __restrict__ padzero) {
  const int t = threadIdx.x;
  // cooperative zero of kpad++vpad (448 uint4 per block, 864 blocks)
  {
    const int bf = (blockIdx.z * 4 + blockIdx.y) * 36 + blockIdx.x;
    uint4* pz = padzero + (size_t)bf * kZeroPerBlk;
    const uint4 zz = {0u, 0u, 0u, 0u};
    pz[t] = zz;
    if (t < kZeroPerBlk - 256) pz[256 + t] = zz;
  }
  const int z = blockIdx.z, tz = z >> 1, b = z & 1;
  const float* src = (tz == 0) ? q : (tz == 1) ? k : v;
  u16* dst = (tz == 0) ? xq : (tz == 1) ? xk : xv;
  const int p0 = blockIdx.x * 64, c0 = blockIdx.y * 64;
  __shared__ float tile[64 * 68];
#pragma unroll
  for (int i = 0; i < 4; ++i) {
    const int c = (t >> 4) + i * 16, p4 = t & 15;
    const float4 val =
        *(const float4*)&src[(size_t)(b * kC + c0 + c) * kHW + p0 + p4 * 4];
    *(float4*)&tile[c * 68 + p4 * 4] = val;
  }
  __syncthreads();
  const int p = t >> 2, cg = t & 3;
#pragma unroll
  for (int i = 0; i < 4; ++i) {
    const int cb = cg * 4 + i * 16;
    uint2 w;
    w.x = pack2(tile[(cb + 0) * 68 + p], tile[(cb + 1) * 68 + p]);
    w.y = pack2(tile[(cb + 2) * 68 + p], tile[(cb + 3) * 68 + p]);
    *(uint2*)&dst[(size_t)(b * kHW + p0 + p) * kC + c0 + cb] = w;
  }
}

// ---------------------------------------------------------------------------
// MFMA GEMM body (64x64x256, bf16 in, fp32 acc). Shared by both GEMM kernels.
// ---------------------------------------------------------------------------
struct GemmAcc {
  f32x4 acc[2][2];
};

__device__ __forceinline__ GemmAcc gemm_body(const u16* __restrict__ A,
                                             const float* __restrict__ Wm,
                                             int m0, int n0, int t,
                                             u16* As, u16* Bs) {
  const int l = t & 63, w = t >> 6, wm = w >> 1, wn = w & 1;
  GemmAcc r;
#pragma unroll
  for (int mf = 0; mf < 2; ++mf)
#pragma unroll
    for (int nf = 0; nf < 2; ++nf) r.acc[mf][nf] = (f32x4){0.f, 0.f, 0.f, 0.f};

  for (int kt = 0; kt < 4; ++kt) {
    const int k0 = kt * 64;
    if (kt) __syncthreads();
#pragma unroll
    for (int j = 0; j < 2; ++j) {  // stage A: 512 x 16B
      const int task = t + j * 256;
      const int rr = task >> 3, ch = task & 7;
      const uint4 val = *(const uint4*)&A[(size_t)(m0 + rr) * kC + k0 + ch * 8];
      const int byteoff = (ch * 16) ^ ((rr & 7) << 4);
      *(uint4*)&As[rr * 64 + (byteoff >> 1)] = val;
    }
#pragma unroll
    for (int j = 0; j < 4; ++j) {  // stage B with fp32->bf16 cvt
      const int task = t + j * 256;
      const int rr = task >> 4, f4 = task & 15;
      const float4 val =
          *(const float4*)&Wm[(size_t)(n0 + rr) * kC + k0 + f4 * 4];
      uint2 pk;
      pk.x = pack2(val.x, val.y);
      pk.y = pack2(val.z, val.w);
      const int byteoff = (f4 * 8) ^ ((rr & 7) << 4);
      *(uint2*)&Bs[rr * 64 + (byteoff >> 1)] = pk;
    }
    __syncthreads();
#pragma unroll
    for (int ks = 0; ks < 2; ++ks) {
      const int bo = ks * 64 + ((l >> 4) << 4);
      short8v a[2], bf[2];
#pragma unroll
      for (int mf = 0; mf < 2; ++mf) {
        const int row = wm * 32 + mf * 16 + (l & 15);
        a[mf] = *(const short8v*)&As[row * 64 + ((bo ^ ((row & 7) << 4)) >> 1)];
      }
#pragma unroll
      for (int nf = 0; nf < 2; ++nf) {
        const int row = wn * 32 + nf * 16 + (l & 15);
        bf[nf] = *(const short8v*)&Bs[row * 64 + ((bo ^ ((row & 7) << 4)) >> 1)];
      }
#pragma unroll
      for (int mf = 0; mf < 2; ++mf)
#pragma unroll
        for (int nf = 0; nf < 2; ++nf)
          r.acc[mf][nf] = __builtin_amdgcn_mfma_f32_16x16x32_bf16(
              a[mf], bf[nf], r.acc[mf][nf], 0, 0, 0);
    }
  }
  return r;
}

// ---------------------------------------------------------------------------
// Fused QKV GEMM. z=0: q -> bf16 [m][256]. z=1/2: k/v -> padded [bh][pp][32].
// ---------------------------------------------------------------------------
__global__ __launch_bounds__(256) void gemm_qkv_kernel(
    const u16* __restrict__ xtq, const u16* __restrict__ xtk,
    const u16* __restrict__ xtv, const float* __restrict__ Wq,
    const float* __restrict__ Wk, const float* __restrict__ Wv,
    u16* __restrict__ qbf, u16* __restrict__ kpad, u16* __restrict__ vpad) {
  __shared__ __align__(16) u16 As[64 * 64];
  __shared__ __align__(16) u16 Bs[64 * 64];
  const int t = threadIdx.x;
  const int z = blockIdx.z;
  const u16* A = (z == 0) ? xtq : (z == 1) ? xtk : xtv;
  const float* Wm = (z == 0) ? Wq : (z == 1) ? Wk : Wv;
  const int m0 = blockIdx.x * 64, n0 = blockIdx.y * 64;
  GemmAcc r = gemm_body(A, Wm, m0, n0, t, As, Bs);

  const int l = t & 63, w = t >> 6, wm = w >> 1, wn = w & 1;
  const int bb = m0 / kHW;  // block never straddles b (2304 % 64 == 0)
  u16* pd = (z == 1) ? kpad : vpad;
#pragma unroll
  for (int mf = 0; mf < 2; ++mf)
#pragma unroll
    for (int nf = 0; nf < 2; ++nf)
#pragma unroll
      for (int i = 0; i < 4; ++i) {
        const int m = m0 + wm * 32 + mf * 16 + ((l >> 4) << 2) + i;
        const int o = n0 + wn * 32 + nf * 16 + (l & 15);
        const float val = r.acc[mf][nf][i];
        if (z == 0) {
          qbf[(size_t)m * kC + o] = f2bf(val);
        } else {
          const int p = m - bb * kHW;
          const int y = p / kW, x = p - y * kW;
          const size_t addr =
              ((size_t)(bb * 8 + (o >> 5)) * kPP + (y + 3) * kPW + (x + 3)) *
                  32 +
              (o & 31);
          pd[addr] = f2bf(val);
        }
      }
}

// FC GEMM: fp32 out + residual
__global__ __launch_bounds__(256) void gemm_fc_kernel(
    const u16* __restrict__ A, const float* __restrict__ Wm,
    const float* __restrict__ Res, float* __restrict__ Out) {
  __shared__ __align__(16) u16 As[64 * 64];
  __shared__ __align__(16) u16 Bs[64 * 64];
  const int t = threadIdx.x;
  const int m0 = blockIdx.x * 64, n0 = blockIdx.y * 64;
  GemmAcc r = gemm_body(A, Wm, m0, n0, t, As, Bs);
  const int l = t & 63, w = t >> 6, wm = w >> 1, wn = w & 1;
  const int bb = m0 / kHW;
#pragma unroll
  for (int mf = 0; mf < 2; ++mf)
#pragma unroll
    for (int nf = 0; nf < 2; ++nf)
#pragma unroll
      for (int i = 0; i < 4; ++i) {
        const int m = m0 + wm * 32 + mf * 16 + ((l >> 4) << 2) + i;
        const int o = n0 + wn * 32 + nf * 16 + (l & 15);
        const int p = m - bb * kHW;
        const size_t addr = ((size_t)(bb * kC + o)) * kHW + p;
        Out[addr] = r.acc[mf][nf][i] + Res[addr];
      }
}

// ---------------------------------------------------------------------------
// Local 7x7 attention. Block = 256 thr (4 waves) = one (b,h) 8x8 tile.
// 4 lanes per pixel split the 49 neighbors (n % 4 == lane>>4).
// ---------------------------------------------------------------------------
#define DOT_U4(accv, r, qb)                                  \
  accv += UPLO(r.x) * qf[qb + 0] + UPHI(r.x) * qf[qb + 1];   \
  accv += UPLO(r.y) * qf[qb + 2] + UPHI(r.y) * qf[qb + 3];   \
  accv += UPLO(r.z) * qf[qb + 4] + UPHI(r.z) * qf[qb + 5];   \
  accv += UPLO(r.w) * qf[qb + 6] + UPHI(r.w) * qf[qb + 7];

#define PV_U4(e, r, ob)                                      \
  of[ob + 0] += e * UPLO(r.x); of[ob + 1] += e * UPHI(r.x);  \
  of[ob + 2] += e * UPLO(r.y); of[ob + 3] += e * UPHI(r.y);  \
  of[ob + 4] += e * UPLO(r.z); of[ob + 5] += e * UPHI(r.z);  \
  of[ob + 6] += e * UPLO(r.w); of[ob + 7] += e * UPHI(r.w);

__global__ __launch_bounds__(256) void attn2_kernel(
    const u16* __restrict__ qbf, const u16* __restrict__ kpad,
    const u16* __restrict__ vpad, u16* __restrict__ att) {
  __shared__ __align__(16) u16 ks_[196 * 40];
  __shared__ __align__(16) u16 vs_[196 * 40];
  const int t = threadIdx.x;
  const int tile = blockIdx.x, bh = blockIdx.y;
  const int byy = tile / 6, bxx = tile % 6;
  const int b = bh >> 3, h = bh & 7;
  const int l = t & 63, w = t >> 6;
  const int pi = w * 16 + (l & 15);
  const int ty = pi >> 3, tx = pi & 7;
  const int ng = l >> 4;
  const int gp = (byy * 8 + ty) * kW + (bxx * 8 + tx);

  const size_t qbase = ((size_t)(b * kHW + gp)) * kC + h * 32;
  const uint4 q0 = *(const uint4*)&qbf[qbase + 0];
  const uint4 q1 = *(const uint4*)&qbf[qbase + 8];
  const uint4 q2 = *(const uint4*)&qbf[qbase + 16];
  const uint4 q3 = *(const uint4*)&qbf[qbase + 24];
  float qf[32];
#define QUNPK(v, base)                                    \
  qf[base + 0] = UPLO(v.x); qf[base + 1] = UPHI(v.x);     \
  qf[base + 2] = UPLO(v.y); qf[base + 3] = UPHI(v.y);     \
  qf[base + 4] = UPLO(v.z); qf[base + 5] = UPHI(v.z);     \
  qf[base + 6] = UPLO(v.w); qf[base + 7] = UPHI(v.w);
  QUNPK(q0, 0) QUNPK(q1, 8) QUNPK(q2, 16) QUNPK(q3, 24)

  const size_t kvbase = (size_t)bh * kPP * 32;
  for (int task = t; task < 1568; task += 256) {
    const int mat = task >= 784;
    const int rem = task - mat * 784;
    const int hp = rem >> 2, ch = rem & 3;
    const int hy = hp / 14, hx = hp - hy * 14;
    const size_t src =
        kvbase + ((size_t)((byy * 8 + hy) * kPW + (bxx * 8 + hx))) * 32 +
        ch * 8;
    const uint4 val = *(const uint4*)&(mat ? vpad : kpad)[src];
    u16* dst = mat ? vs_ : ks_;
    *(uint4*)&dst[hp * 40 + ch * 8] = val;
  }
  __syncthreads();

  float s[13];
  float pm = -1e30f;
#pragma unroll
  for (int nn = 0; nn < 13; ++nn) {
    const int n = nn * 4 + ng;
    float sc = -1e30f;
    if (n < 49) {
      const int ky = n / 7, kx = n - ky * 7;
      const int pp = (ty + ky) * 14 + (tx + kx);
      const u16* kr = &ks_[pp * 40];
      const uint4 r0 = *(const uint4*)&kr[0];
      const uint4 r1 = *(const uint4*)&kr[8];
      const uint4 r2 = *(const uint4*)&kr[16];
      const uint4 r3 = *(const uint4*)&kr[24];
      float d = 0.f;
      DOT_U4(d, r0, 0) DOT_U4(d, r1, 8) DOT_U4(d, r2, 16) DOT_U4(d, r3, 24)
      sc = d * kInvTemp;
    }
    s[nn] = sc;
    pm = fmaxf(pm, sc);
  }
  pm = fmaxf(pm, __shfl_xor(pm, 16));
  pm = fmaxf(pm, __shfl_xor(pm, 32));
  float zs = 0.f;
#pragma unroll
  for (int nn = 0; nn < 13; ++nn) {
    const float e = __expf(s[nn] - pm);
    s[nn] = e;
    zs += e;
  }
  zs += __shfl_xor(zs, 16);
  zs += __shfl_xor(zs, 32);
  const float rinv = 1.0f / zs;

  float of[32];
#pragma unroll
  for (int d = 0; d < 32; ++d) of[d] = 0.f;
#pragma unroll
  for (int nn = 0; nn < 13; ++nn) {
    const int n = nn * 4 + ng;
    if (n < 49) {
      const int ky = n / 7, kx = n - ky * 7;
      const int pp = (ty + ky) * 14 + (tx + kx);
      const u16* vr = &vs_[pp * 40];
      const uint4 r0 = *(const uint4*)&vr[0];
      const uint4 r1 = *(const uint4*)&vr[8];
      const uint4 r2 = *(const uint4*)&vr[16];
      const uint4 r3 = *(const uint4*)&vr[24];
      const float e = s[nn];
      PV_U4(e, r0, 0) PV_U4(e, r1, 8) PV_U4(e, r2, 16) PV_U4(e, r3, 24)
    }
  }
#pragma unroll
  for (int d = 0; d < 32; ++d) {
    of[d] += __shfl_xor(of[d], 16);
    of[d] += __shfl_xor(of[d], 32);
  }
  float seg[8];
#pragma unroll
  for (int j = 0; j < 8; ++j) {
    const float a01 = (ng == 0) ? of[j] : of[8 + j];
    const float a23 = (ng == 2) ? of[16 + j] : of[24 + j];
    seg[j] = (ng < 2) ? a01 : a23;
  }
  uint4 out;
  out.x = pack2(seg[0] * rinv, seg[1] * rinv);
  out.y = pack2(seg[2] * rinv, seg[3] * rinv);
  out.z = pack2(seg[4] * rinv, seg[5] * rinv);
  out.w = pack2(seg[6] * rinv, seg[7] * rinv);
  *(uint4*)&att[((size_t)(b * kHW + gp)) * kC + h * 32 + ng * 8] = out;
}

}  // namespace

extern "C" void kernel_launch(void* const* d_in, const int* in_sizes, int n_in,
                              void* d_out, int out_size, void* d_ws,
                              size_t ws_size, hipStream_t stream) {
  const float* q = (const float*)d_in[0];
  const float* k = (const float*)d_in[1];
  const float* v = (const float*)d_in[2];
  const float* Wq = (const float*)d_in[3];
  const float* Wk = (const float*)d_in[4];
  const float* Wv = (const float*)d_in[5];
  const float* Wfc = (const float*)d_in[6];
  float* out = (float*)d_out;

  char* ws = (char*)d_ws;
  u16* xtq = (u16*)(ws);
  u16* xtk = (u16*)(ws + XT_BYTES);
  u16* xtv = (u16*)(ws + 2 * XT_BYTES);
  u16* kpad = (u16*)(ws + 3 * XT_BYTES);
  u16* vpad = (u16*)(ws + 3 * XT_BYTES + KPAD_BYTES);
  u16* qbf = (u16*)(ws + 3 * XT_BYTES + 2 * KPAD_BYTES);
  u16* att = xtq;  // xtq dead after q-GEMM; attn runs later in-stream

  tcvt_kernel<<<dim3(kHW / 64, kC / 64, 6), 256, 0, stream>>>(
      q, k, v, xtq, xtk, xtv, (uint4*)kpad);

  gemm_qkv_kernel<<<dim3(kM / 64, kC / 64, 3), 256, 0, stream>>>(
      xtq, xtk, xtv, Wq, Wk, Wv, qbf, kpad, vpad);

  attn2_kernel<<<dim3(36, 16), 256, 0, stream>>>(qbf, kpad, vpad, att);

  gemm_fc_kernel<<<dim3(kM / 64, kC / 64), 256, 0, stream>>>(att, Wfc, q, out);
}

// Round 4
// 57.613 us; speedup vs baseline: 3.2333x; 1.0887x over previous
//
#include <hip/hip_runtime.h>

typedef unsigned int u32;
typedef unsigned short u16;
typedef __attribute__((ext_vector_type(8))) short short8v;
typedef __attribute__((ext_vector_type(4))) float f32x4;

namespace {

constexpr int kH = 48, kW = 48, kHW = kH * kW;     // 2304
constexpr int kC = 256;
constexpr int kB = 2;
constexpr int kM = kB * kHW;                        // 4608 GEMM rows
constexpr int kPH = 54, kPW = 56, kPP = kPH * kPW;  // padded kv grid (3024)
constexpr float kInvTemp = 0.17677669529663687f;    // 1/sqrt(32)

constexpr size_t KPAD_U16 = (size_t)16 * kPP * 32;  // 1,548,288 u16 per mat
constexpr size_t QBF_U16 = (size_t)kM * kC;         // 1,179,648 u16
// border zeroing: 720 border pixels/plane x 16 planes x 2 mats x 4 uint4
constexpr int kZeroTasks = 720 * 16 * 2 * 4;        // 92,160
constexpr int kZeroPerBlk = 107;                    // 864 blocks x 107 >= 92160

__device__ __forceinline__ u16 f2bf(float f) {
  u32 u = __builtin_bit_cast(u32, f);
  return (u16)((u + 0x7fffu + ((u >> 16) & 1u)) >> 16);
}
__device__ __forceinline__ u32 pack2(float lo, float hi) {
  return (u32)f2bf(lo) | ((u32)f2bf(hi) << 16);
}
__device__ __forceinline__ float f4e(const float4 v, int i) {
  return (i == 0) ? v.x : (i == 1) ? v.y : (i == 2) ? v.z : v.w;
}
#define UPLO(u) __builtin_bit_cast(float, (u32)((u) << 16))
#define UPHI(u) __builtin_bit_cast(float, (u32)((u) & 0xffff0000u))

// ---------------------------------------------------------------------------
// Fused QKV GEMM, A staged directly from fp32 [b][c][p] (in-LDS transpose).
// z=0: q -> bf16 [m][256].  z=1/2: k/v -> zero-padded [bh][54*56][32].
// Also zeroes the pad borders (disjoint from interior epilogue writes).
// ---------------------------------------------------------------------------
__global__ __launch_bounds__(256) void gemm_qkv_kernel(
    const float* __restrict__ q, const float* __restrict__ k,
    const float* __restrict__ v, const float* __restrict__ Wq,
    const float* __restrict__ Wk, const float* __restrict__ Wv,
    u16* __restrict__ qbf, u16* __restrict__ kpad, u16* __restrict__ vpad) {
  __shared__ __align__(16) u16 As[64 * 64];
  __shared__ __align__(16) u16 Bs[64 * 64];
  const int t = threadIdx.x;

  // ---- border zeroing (1.5 MB total across the 864 blocks) ----
  {
    const int bid = (blockIdx.z * 4 + blockIdx.y) * 72 + blockIdx.x;
    const int T = bid * kZeroPerBlk + t;
    if (t < kZeroPerBlk && T < kZeroTasks) {
      const int ch = T & 3, rest = T >> 2;     // rest < 23040
      const int pm = rest / 720, bi = rest - pm * 720;
      int y, x;
      if (bi < 336) {  // full rows 0,1,2,51,52,53
        const int r = bi / 56, c = bi - (bi / 56) * 56;
        y = (r < 3) ? r : 48 + r;
        x = c;
      } else {  // rows 3..50, cols {0,1,2,51..55}
        const int r = (bi - 336) >> 3, c = (bi - 336) & 7;
        y = 3 + r;
        x = (c < 3) ? c : c + 48;
      }
      u16* pb = (pm >= 16) ? vpad : kpad;
      const uint4 zz = {0u, 0u, 0u, 0u};
      *(uint4*)&pb[((size_t)(pm & 15) * kPP + y * kPW + x) * 32 + ch * 8] = zz;
    }
  }

  const int z = blockIdx.z;
  const float* X = (z == 0) ? q : (z == 1) ? k : v;
  const float* Wm = (z == 0) ? Wq : (z == 1) ? Wk : Wv;
  const int m0 = blockIdx.x * 64, n0 = blockIdx.y * 64;
  const int bb = m0 / kHW, p0 = m0 - bb * kHW;  // 2304%64==0: no straddle
  const int l = t & 63, w = t >> 6, wm = w >> 1, wn = w & 1;
  const int mq = t & 15, kq = t >> 4;

  f32x4 acc[2][2];
#pragma unroll
  for (int mf = 0; mf < 2; ++mf)
#pragma unroll
    for (int nf = 0; nf < 2; ++nf) acc[mf][nf] = (f32x4){0.f, 0.f, 0.f, 0.f};

  for (int kt = 0; kt < 4; ++kt) {
    const int k0 = kt * 64;
    if (kt) __syncthreads();
    // A stage: read 4 c-rows x float4 (coalesced), 4x4 register transpose,
    // pack bf16, 8B LDS writes (swizzle has no bit-3 term: 16B reads intact).
    {
      const float* ab =
          X + ((size_t)(bb * kC + k0 + kq * 4)) * kHW + p0 + mq * 4;
      const float4 r0 = *(const float4*)(ab);
      const float4 r1 = *(const float4*)(ab + kHW);
      const float4 r2 = *(const float4*)(ab + 2 * kHW);
      const float4 r3 = *(const float4*)(ab + 3 * kHW);
#pragma unroll
      for (int i = 0; i < 4; ++i) {
        const int ml = mq * 4 + i;
        uint2 pk;
        pk.x = pack2(f4e(r0, i), f4e(r1, i));
        pk.y = pack2(f4e(r2, i), f4e(r3, i));
        const int bo = (kq * 8) ^ ((ml & 7) << 4);
        *(uint2*)&As[ml * 64 + (bo >> 1)] = pk;
      }
    }
    // B stage: fp32 W[o][c] -> bf16, same swizzle
#pragma unroll
    for (int j = 0; j < 4; ++j) {
      const int task = t + j * 256;
      const int rr = task >> 4, f4i = task & 15;
      const float4 val =
          *(const float4*)&Wm[(size_t)(n0 + rr) * kC + k0 + f4i * 4];
      uint2 pk;
      pk.x = pack2(val.x, val.y);
      pk.y = pack2(val.z, val.w);
      const int bo = (f4i * 8) ^ ((rr & 7) << 4);
      *(uint2*)&Bs[rr * 64 + (bo >> 1)] = pk;
    }
    __syncthreads();
#pragma unroll
    for (int ks = 0; ks < 2; ++ks) {
      const int bo = ks * 64 + ((l >> 4) << 4);
      short8v a[2], bfr[2];
#pragma unroll
      for (int mf = 0; mf < 2; ++mf) {
        const int row = wm * 32 + mf * 16 + (l & 15);
        a[mf] = *(const short8v*)&As[row * 64 + ((bo ^ ((row & 7) << 4)) >> 1)];
      }
#pragma unroll
      for (int nf = 0; nf < 2; ++nf) {
        const int row = wn * 32 + nf * 16 + (l & 15);
        bfr[nf] =
            *(const short8v*)&Bs[row * 64 + ((bo ^ ((row & 7) << 4)) >> 1)];
      }
#pragma unroll
      for (int mf = 0; mf < 2; ++mf)
#pragma unroll
        for (int nf = 0; nf < 2; ++nf)
          acc[mf][nf] = __builtin_amdgcn_mfma_f32_16x16x32_bf16(
              a[mf], bfr[nf], acc[mf][nf], 0, 0, 0);
    }
  }

  u16* pd = (z == 1) ? kpad : vpad;
#pragma unroll
  for (int mf = 0; mf < 2; ++mf)
#pragma unroll
    for (int nf = 0; nf < 2; ++nf)
#pragma unroll
      for (int i = 0; i < 4; ++i) {
        const int m = m0 + wm * 32 + mf * 16 + ((l >> 4) << 2) + i;
        const int o = n0 + wn * 32 + nf * 16 + (l & 15);
        const float val = acc[mf][nf][i];
        if (z == 0) {
          qbf[(size_t)m * kC + o] = f2bf(val);
        } else {
          const int p = m - bb * kHW;
          const int y = p / kW, x = p - (p / kW) * kW;
          pd[((size_t)(bb * 8 + (o >> 5)) * kPP + (y + 3) * kPW + (x + 3)) *
                 32 +
             (o & 31)] = f2bf(val);
        }
      }
}

// ---------------------------------------------------------------------------
// FC GEMM with swapped operands: A = Wfc (M=o), B = att (N=p). C cols map to
// pixels -> fp32 stores/residual reads are 16-lane contiguous.
// ---------------------------------------------------------------------------
__global__ __launch_bounds__(256) void gemm_fc_kernel(
    const u16* __restrict__ att, const float* __restrict__ Wfc,
    const float* __restrict__ Res, float* __restrict__ Out) {
  __shared__ __align__(16) u16 As[64 * 64];  // Wfc rows (o)
  __shared__ __align__(16) u16 Bs[64 * 64];  // att rows (pixels)
  const int t = threadIdx.x;
  const int q0 = blockIdx.x * 64;  // pixel block (global over 4608)
  const int o0 = blockIdx.y * 64;
  const int bb = q0 / kHW, p0 = q0 - bb * kHW;
  const int l = t & 63, w = t >> 6, wm = w >> 1, wn = w & 1;

  f32x4 acc[2][2];
#pragma unroll
  for (int mf = 0; mf < 2; ++mf)
#pragma unroll
    for (int nf = 0; nf < 2; ++nf) acc[mf][nf] = (f32x4){0.f, 0.f, 0.f, 0.f};

  for (int kt = 0; kt < 4; ++kt) {
    const int k0 = kt * 64;
    if (kt) __syncthreads();
#pragma unroll
    for (int j = 0; j < 4; ++j) {  // As <- Wfc (cvt)
      const int task = t + j * 256;
      const int rr = task >> 4, f4i = task & 15;
      const float4 val =
          *(const float4*)&Wfc[(size_t)(o0 + rr) * kC + k0 + f4i * 4];
      uint2 pk;
      pk.x = pack2(val.x, val.y);
      pk.y = pack2(val.z, val.w);
      const int bo = (f4i * 8) ^ ((rr & 7) << 4);
      *(uint2*)&As[rr * 64 + (bo >> 1)] = pk;
    }
#pragma unroll
    for (int j = 0; j < 2; ++j) {  // Bs <- att (bf16, k-contig)
      const int task = t + j * 256;
      const int rr = task >> 3, ch = task & 7;
      const uint4 val = *(const uint4*)&att[(size_t)(q0 + rr) * kC + k0 + ch * 8];
      const int bo = (ch * 16) ^ ((rr & 7) << 4);
      *(uint4*)&Bs[rr * 64 + (bo >> 1)] = val;
    }
    __syncthreads();
#pragma unroll
    for (int ks = 0; ks < 2; ++ks) {
      const int bo = ks * 64 + ((l >> 4) << 4);
      short8v a[2], bfr[2];
#pragma unroll
      for (int mf = 0; mf < 2; ++mf) {
        const int row = wm * 32 + mf * 16 + (l & 15);
        a[mf] = *(const short8v*)&As[row * 64 + ((bo ^ ((row & 7) << 4)) >> 1)];
      }
#pragma unroll
      for (int nf = 0; nf < 2; ++nf) {
        const int row = wn * 32 + nf * 16 + (l & 15);
        bfr[nf] =
            *(const short8v*)&Bs[row * 64 + ((bo ^ ((row & 7) << 4)) >> 1)];
      }
#pragma unroll
      for (int mf = 0; mf < 2; ++mf)
#pragma unroll
        for (int nf = 0; nf < 2; ++nf)
          acc[mf][nf] = __builtin_amdgcn_mfma_f32_16x16x32_bf16(
              a[mf], bfr[nf], acc[mf][nf], 0, 0, 0);
    }
  }
#pragma unroll
  for (int mf = 0; mf < 2; ++mf)
#pragma unroll
    for (int nf = 0; nf < 2; ++nf)
#pragma unroll
      for (int i = 0; i < 4; ++i) {
        const int o = o0 + wm * 32 + mf * 16 + ((l >> 4) << 2) + i;
        const int p = p0 + wn * 32 + nf * 16 + (l & 15);
        const size_t addr = ((size_t)(bb * kC + o)) * kHW + p;
        Out[addr] = acc[mf][nf][i] + Res[addr];
      }
}

// ---------------------------------------------------------------------------
// Local 7x7 attention. Block = 256 thr (4 waves) = one (b,h) 8x8 tile.
// 4 lanes per pixel split the 49 neighbors (n % 4 == lane>>4).
// ---------------------------------------------------------------------------
#define DOT_U4(accv, r, qb)                                  \
  accv += UPLO(r.x) * qf[qb + 0] + UPHI(r.x) * qf[qb + 1];   \
  accv += UPLO(r.y) * qf[qb + 2] + UPHI(r.y) * qf[qb + 3];   \
  accv += UPLO(r.z) * qf[qb + 4] + UPHI(r.z) * qf[qb + 5];   \
  accv += UPLO(r.w) * qf[qb + 6] + UPHI(r.w) * qf[qb + 7];

#define PV_U4(e, r, ob)                                      \
  of[ob + 0] += e * UPLO(r.x); of[ob + 1] += e * UPHI(r.x);  \
  of[ob + 2] += e * UPLO(r.y); of[ob + 3] += e * UPHI(r.y);  \
  of[ob + 4] += e * UPLO(r.z); of[ob + 5] += e * UPHI(r.z);  \
  of[ob + 6] += e * UPLO(r.w); of[ob + 7] += e * UPHI(r.w);

__global__ __launch_bounds__(256) void attn2_kernel(
    const u16* __restrict__ qbf, const u16* __restrict__ kpad,
    const u16* __restrict__ vpad, u16* __restrict__ att) {
  __shared__ __align__(16) u16 ks_[196 * 40];
  __shared__ __align__(16) u16 vs_[196 * 40];
  const int t = threadIdx.x;
  const int tile = blockIdx.x, bh = blockIdx.y;
  const int byy = tile / 6, bxx = tile % 6;
  const int b = bh >> 3, h = bh & 7;
  const int l = t & 63, w = t >> 6;
  const int pi = w * 16 + (l & 15);
  const int ty = pi >> 3, tx = pi & 7;
  const int ng = l >> 4;
  const int gp = (byy * 8 + ty) * kW + (bxx * 8 + tx);

  const size_t qbase = ((size_t)(b * kHW + gp)) * kC + h * 32;
  const uint4 q0 = *(const uint4*)&qbf[qbase + 0];
  const uint4 q1 = *(const uint4*)&qbf[qbase + 8];
  const uint4 q2 = *(const uint4*)&qbf[qbase + 16];
  const uint4 q3 = *(const uint4*)&qbf[qbase + 24];
  float qf[32];
#define QUNPK(v, base)                                    \
  qf[base + 0] = UPLO(v.x); qf[base + 1] = UPHI(v.x);     \
  qf[base + 2] = UPLO(v.y); qf[base + 3] = UPHI(v.y);     \
  qf[base + 4] = UPLO(v.z); qf[base + 5] = UPHI(v.z);     \
  qf[base + 6] = UPLO(v.w); qf[base + 7] = UPHI(v.w);
  QUNPK(q0, 0) QUNPK(q1, 8) QUNPK(q2, 16) QUNPK(q3, 24)

  const size_t kvbase = (size_t)bh * kPP * 32;
  for (int task = t; task < 1568; task += 256) {
    const int mat = task >= 784;
    const int rem = task - mat * 784;
    const int hp = rem >> 2, ch = rem & 3;
    const int hy = hp / 14, hx = hp - hy * 14;
    const size_t src =
        kvbase + ((size_t)((byy * 8 + hy) * kPW + (bxx * 8 + hx))) * 32 +
        ch * 8;
    const uint4 val = *(const uint4*)&(mat ? vpad : kpad)[src];
    u16* dst = mat ? vs_ : ks_;
    *(uint4*)&dst[hp * 40 + ch * 8] = val;
  }
  __syncthreads();

  float s[13];
  float pm = -1e30f;
#pragma unroll
  for (int nn = 0; nn < 13; ++nn) {
    const int n = nn * 4 + ng;
    float sc = -1e30f;
    if (n < 49) {
      const int ky = n / 7, kx = n - ky * 7;
      const int pp = (ty + ky) * 14 + (tx + kx);
      const u16* kr = &ks_[pp * 40];
      const uint4 r0 = *(const uint4*)&kr[0];
      const uint4 r1 = *(const uint4*)&kr[8];
      const uint4 r2 = *(const uint4*)&kr[16];
      const uint4 r3 = *(const uint4*)&kr[24];
      float d = 0.f;
      DOT_U4(d, r0, 0) DOT_U4(d, r1, 8) DOT_U4(d, r2, 16) DOT_U4(d, r3, 24)
      sc = d * kInvTemp;
    }
    s[nn] = sc;
    pm = fmaxf(pm, sc);
  }
  pm = fmaxf(pm, __shfl_xor(pm, 16));
  pm = fmaxf(pm, __shfl_xor(pm, 32));
  float zs = 0.f;
#pragma unroll
  for (int nn = 0; nn < 13; ++nn) {
    const float e = __expf(s[nn] - pm);
    s[nn] = e;
    zs += e;
  }
  zs += __shfl_xor(zs, 16);
  zs += __shfl_xor(zs, 32);
  const float rinv = 1.0f / zs;

  float of[32];
#pragma unroll
  for (int d = 0; d < 32; ++d) of[d] = 0.f;
#pragma unroll
  for (int nn = 0; nn < 13; ++nn) {
    const int n = nn * 4 + ng;
    if (n < 49) {
      const int ky = n / 7, kx = n - ky * 7;
      const int pp = (ty + ky) * 14 + (tx + kx);
      const u16* vr = &vs_[pp * 40];
      const uint4 r0 = *(const uint4*)&vr[0];
      const uint4 r1 = *(const uint4*)&vr[8];
      const uint4 r2 = *(const uint4*)&vr[16];
      const uint4 r3 = *(const uint4*)&vr[24];
      const float e = s[nn];
      PV_U4(e, r0, 0) PV_U4(e, r1, 8) PV_U4(e, r2, 16) PV_U4(e, r3, 24)
    }
  }
#pragma unroll
  for (int d = 0; d < 32; ++d) {
    of[d] += __shfl_xor(of[d], 16);
    of[d] += __shfl_xor(of[d], 32);
  }
  float seg[8];
#pragma unroll
  for (int j = 0; j < 8; ++j) {
    const float a01 = (ng == 0) ? of[j] : of[8 + j];
    const float a23 = (ng == 2) ? of[16 + j] : of[24 + j];
    seg[j] = (ng < 2) ? a01 : a23;
  }
  uint4 outv;
  outv.x = pack2(seg[0] * rinv, seg[1] * rinv);
  outv.y = pack2(seg[2] * rinv, seg[3] * rinv);
  outv.z = pack2(seg[4] * rinv, seg[5] * rinv);
  outv.w = pack2(seg[6] * rinv, seg[7] * rinv);
  *(uint4*)&att[((size_t)(b * kHW + gp)) * kC + h * 32 + ng * 8] = outv;
}

}  // namespace

extern "C" void kernel_launch(void* const* d_in, const int* in_sizes, int n_in,
                              void* d_out, int out_size, void* d_ws,
                              size_t ws_size, hipStream_t stream) {
  const float* q = (const float*)d_in[0];
  const float* k = (const float*)d_in[1];
  const float* v = (const float*)d_in[2];
  const float* Wq = (const float*)d_in[3];
  const float* Wk = (const float*)d_in[4];
  const float* Wv = (const float*)d_in[5];
  const float* Wfc = (const float*)d_in[6];
  float* out = (float*)d_out;

  u16* ws16 = (u16*)d_ws;
  u16* kpad = ws16;
  u16* vpad = ws16 + KPAD_U16;
  u16* qbf = ws16 + 2 * KPAD_U16;
  u16* att = qbf + QBF_U16;

  gemm_qkv_kernel<<<dim3(kM / 64, kC / 64, 3), 256, 0, stream>>>(
      q, k, v, Wq, Wk, Wv, qbf, kpad, vpad);

  attn2_kernel<<<dim3(36, 16), 256, 0, stream>>>(qbf, kpad, vpad, att);

  gemm_fc_kernel<<<dim3(kM / 64, kC / 64), 256, 0, stream>>>(att, Wfc, q, out);
}

// Round 5
// 52.428 us; speedup vs baseline: 3.5530x; 1.0989x over previous
//
#include <hip/hip_runtime.h>

typedef unsigned int u32;
typedef unsigned short u16;
typedef __attribute__((ext_vector_type(8))) _Float16 f16x8;
typedef __attribute__((ext_vector_type(2))) _Float16 f16x2;
typedef __attribute__((ext_vector_type(4))) float f32x4;

namespace {

constexpr int kH = 48, kW = 48, kHW = kH * kW;     // 2304
constexpr int kC = 256;
constexpr int kB = 2;
constexpr int kM = kB * kHW;                        // 4608 GEMM rows
constexpr int kPH = 54, kPW = 56, kPP = kPH * kPW;  // padded kv grid (3024)
constexpr float kInvTemp = 0.17677669529663687f;    // 1/sqrt(32)

constexpr size_t KPAD_U16 = (size_t)16 * kPP * 32;  // 1,548,288 u16 per mat
constexpr size_t QBF_U16 = (size_t)kM * kC;         // 1,179,648 u16
// border zeroing: 720 border pixels/plane x 16 planes x 2 mats x 4 uint4
constexpr int kZeroTasks = 720 * 16 * 2 * 4;        // 92,160
constexpr int kZeroPerBlk = 107;                    // 864 blocks x 107 >= 92160

// 1-instruction f32x2 -> f16x2 pack (v_cvt_pkrtz_f16_f32)
__device__ __forceinline__ u32 pack2h(float lo, float hi) {
  return __builtin_bit_cast(u32, __builtin_amdgcn_cvt_pkrtz(lo, hi));
}
__device__ __forceinline__ u16 f2h(float f) {
  return __builtin_bit_cast(u16, (_Float16)f);
}
__device__ __forceinline__ float f4e(const float4 v, int i) {
  return (i == 0) ? v.x : (i == 1) ? v.y : (i == 2) ? v.z : v.w;
}

// ---------------------------------------------------------------------------
// Fused QKV GEMM, A staged directly from fp32 [b][c][p] (in-LDS transpose).
// z=0: q -> f16 [m][256].  z=1/2: k/v -> zero-padded f16 [bh][54*56][32].
// Also zeroes the pad borders (disjoint from interior epilogue writes).
// ---------------------------------------------------------------------------
__global__ __launch_bounds__(256) void gemm_qkv_kernel(
    const float* __restrict__ q, const float* __restrict__ k,
    const float* __restrict__ v, const float* __restrict__ Wq,
    const float* __restrict__ Wk, const float* __restrict__ Wv,
    u16* __restrict__ qbf, u16* __restrict__ kpad, u16* __restrict__ vpad) {
  __shared__ __align__(16) u16 As[64 * 64];
  __shared__ __align__(16) u16 Bs[64 * 64];
  const int t = threadIdx.x;

  // ---- border zeroing (1.5 MB total across the 864 blocks) ----
  {
    const int bid = (blockIdx.z * 4 + blockIdx.y) * 72 + blockIdx.x;
    const int T = bid * kZeroPerBlk + t;
    if (t < kZeroPerBlk && T < kZeroTasks) {
      const int ch = T & 3, rest = T >> 2;  // rest < 23040
      const int pm = rest / 720, bi = rest - pm * 720;
      int y, x;
      if (bi < 336) {  // full rows 0,1,2,51,52,53
        const int r = bi / 56, c = bi - (bi / 56) * 56;
        y = (r < 3) ? r : 48 + r;
        x = c;
      } else {  // rows 3..50, cols {0,1,2,51..55}
        const int r = (bi - 336) >> 3, c = (bi - 336) & 7;
        y = 3 + r;
        x = (c < 3) ? c : c + 48;
      }
      u16* pb = (pm >= 16) ? vpad : kpad;
      const uint4 zz = {0u, 0u, 0u, 0u};
      *(uint4*)&pb[((size_t)(pm & 15) * kPP + y * kPW + x) * 32 + ch * 8] = zz;
    }
  }

  const int z = blockIdx.z;
  const float* X = (z == 0) ? q : (z == 1) ? k : v;
  const float* Wm = (z == 0) ? Wq : (z == 1) ? Wk : Wv;
  const int m0 = blockIdx.x * 64, n0 = blockIdx.y * 64;
  const int bb = m0 / kHW, p0 = m0 - bb * kHW;  // 2304%64==0: no straddle
  const int l = t & 63, w = t >> 6, wm = w >> 1, wn = w & 1;
  const int mq = t & 15, kq = t >> 4;

  f32x4 acc[2][2];
#pragma unroll
  for (int mf = 0; mf < 2; ++mf)
#pragma unroll
    for (int nf = 0; nf < 2; ++nf) acc[mf][nf] = (f32x4){0.f, 0.f, 0.f, 0.f};

  for (int kt = 0; kt < 4; ++kt) {
    const int k0 = kt * 64;
    if (kt) __syncthreads();
    // A stage: 4 coalesced c-row float4 reads, 4x4 register transpose,
    // pkrtz pack, 8B LDS writes (swizzle bit-4 only: 16B reads intact).
    {
      const float* ab =
          X + ((size_t)(bb * kC + k0 + kq * 4)) * kHW + p0 + mq * 4;
      const float4 r0 = *(const float4*)(ab);
      const float4 r1 = *(const float4*)(ab + kHW);
      const float4 r2 = *(const float4*)(ab + 2 * kHW);
      const float4 r3 = *(const float4*)(ab + 3 * kHW);
#pragma unroll
      for (int i = 0; i < 4; ++i) {
        const int ml = mq * 4 + i;
        uint2 pk;
        pk.x = pack2h(f4e(r0, i), f4e(r1, i));
        pk.y = pack2h(f4e(r2, i), f4e(r3, i));
        const int bo = (kq * 8) ^ ((ml & 7) << 4);
        *(uint2*)&As[ml * 64 + (bo >> 1)] = pk;
      }
    }
    // B stage: fp32 W[o][c] -> f16, same swizzle
#pragma unroll
    for (int j = 0; j < 4; ++j) {
      const int task = t + j * 256;
      const int rr = task >> 4, f4i = task & 15;
      const float4 val =
          *(const float4*)&Wm[(size_t)(n0 + rr) * kC + k0 + f4i * 4];
      uint2 pk;
      pk.x = pack2h(val.x, val.y);
      pk.y = pack2h(val.z, val.w);
      const int bo = (f4i * 8) ^ ((rr & 7) << 4);
      *(uint2*)&Bs[rr * 64 + (bo >> 1)] = pk;
    }
    __syncthreads();
#pragma unroll
    for (int ks = 0; ks < 2; ++ks) {
      const int bo = ks * 64 + ((l >> 4) << 4);
      f16x8 a[2], bfr[2];
#pragma unroll
      for (int mf = 0; mf < 2; ++mf) {
        const int row = wm * 32 + mf * 16 + (l & 15);
        a[mf] = *(const f16x8*)&As[row * 64 + ((bo ^ ((row & 7) << 4)) >> 1)];
      }
#pragma unroll
      for (int nf = 0; nf < 2; ++nf) {
        const int row = wn * 32 + nf * 16 + (l & 15);
        bfr[nf] =
            *(const f16x8*)&Bs[row * 64 + ((bo ^ ((row & 7) << 4)) >> 1)];
      }
#pragma unroll
      for (int mf = 0; mf < 2; ++mf)
#pragma unroll
        for (int nf = 0; nf < 2; ++nf)
          acc[mf][nf] = __builtin_amdgcn_mfma_f32_16x16x32_f16(
              a[mf], bfr[nf], acc[mf][nf], 0, 0, 0);
    }
  }

  u16* pd = (z == 1) ? kpad : vpad;
#pragma unroll
  for (int mf = 0; mf < 2; ++mf)
#pragma unroll
    for (int nf = 0; nf < 2; ++nf)
#pragma unroll
      for (int i = 0; i < 4; ++i) {
        const int m = m0 + wm * 32 + mf * 16 + ((l >> 4) << 2) + i;
        const int o = n0 + wn * 32 + nf * 16 + (l & 15);
        const float val = acc[mf][nf][i];
        if (z == 0) {
          qbf[(size_t)m * kC + o] = f2h(val);
        } else {
          const int p = m - bb * kHW;
          const int y = p / kW, x = p - (p / kW) * kW;
          pd[((size_t)(bb * 8 + (o >> 5)) * kPP + (y + 3) * kPW + (x + 3)) *
                 32 +
             (o & 31)] = f2h(val);
        }
      }
}

// ---------------------------------------------------------------------------
// FC GEMM with swapped operands: A = Wfc (M=o), B = att (N=p). C cols map to
// pixels -> fp32 stores/residual reads are 16-lane contiguous.
// ---------------------------------------------------------------------------
__global__ __launch_bounds__(256) void gemm_fc_kernel(
    const u16* __restrict__ att, const float* __restrict__ Wfc,
    const float* __restrict__ Res, float* __restrict__ Out) {
  __shared__ __align__(16) u16 As[64 * 64];  // Wfc rows (o)
  __shared__ __align__(16) u16 Bs[64 * 64];  // att rows (pixels)
  const int t = threadIdx.x;
  const int q0 = blockIdx.x * 64;  // pixel block (global over 4608)
  const int o0 = blockIdx.y * 64;
  const int bb = q0 / kHW, p0 = q0 - bb * kHW;
  const int l = t & 63, w = t >> 6, wm = w >> 1, wn = w & 1;

  f32x4 acc[2][2];
#pragma unroll
  for (int mf = 0; mf < 2; ++mf)
#pragma unroll
    for (int nf = 0; nf < 2; ++nf) acc[mf][nf] = (f32x4){0.f, 0.f, 0.f, 0.f};

  for (int kt = 0; kt < 4; ++kt) {
    const int k0 = kt * 64;
    if (kt) __syncthreads();
#pragma unroll
    for (int j = 0; j < 4; ++j) {  // As <- Wfc (cvt)
      const int task = t + j * 256;
      const int rr = task >> 4, f4i = task & 15;
      const float4 val =
          *(const float4*)&Wfc[(size_t)(o0 + rr) * kC + k0 + f4i * 4];
      uint2 pk;
      pk.x = pack2h(val.x, val.y);
      pk.y = pack2h(val.z, val.w);
      const int bo = (f4i * 8) ^ ((rr & 7) << 4);
      *(uint2*)&As[rr * 64 + (bo >> 1)] = pk;
    }
#pragma unroll
    for (int j = 0; j < 2; ++j) {  // Bs <- att (f16, k-contig)
      const int task = t + j * 256;
      const int rr = task >> 3, ch = task & 7;
      const uint4 val =
          *(const uint4*)&att[(size_t)(q0 + rr) * kC + k0 + ch * 8];
      const int bo = (ch * 16) ^ ((rr & 7) << 4);
      *(uint4*)&Bs[rr * 64 + (bo >> 1)] = val;
    }
    __syncthreads();
#pragma unroll
    for (int ks = 0; ks < 2; ++ks) {
      const int bo = ks * 64 + ((l >> 4) << 4);
      f16x8 a[2], bfr[2];
#pragma unroll
      for (int mf = 0; mf < 2; ++mf) {
        const int row = wm * 32 + mf * 16 + (l & 15);
        a[mf] = *(const f16x8*)&As[row * 64 + ((bo ^ ((row & 7) << 4)) >> 1)];
      }
#pragma unroll
      for (int nf = 0; nf < 2; ++nf) {
        const int row = wn * 32 + nf * 16 + (l & 15);
        bfr[nf] =
            *(const f16x8*)&Bs[row * 64 + ((bo ^ ((row & 7) << 4)) >> 1)];
      }
#pragma unroll
      for (int mf = 0; mf < 2; ++mf)
#pragma unroll
        for (int nf = 0; nf < 2; ++nf)
          acc[mf][nf] = __builtin_amdgcn_mfma_f32_16x16x32_f16(
              a[mf], bfr[nf], acc[mf][nf], 0, 0, 0);
    }
  }
#pragma unroll
  for (int mf = 0; mf < 2; ++mf)
#pragma unroll
    for (int nf = 0; nf < 2; ++nf)
#pragma unroll
      for (int i = 0; i < 4; ++i) {
        const int o = o0 + wm * 32 + mf * 16 + ((l >> 4) << 2) + i;
        const int p = p0 + wn * 32 + nf * 16 + (l & 15);
        const size_t addr = ((size_t)(bb * kC + o)) * kHW + p;
        Out[addr] = acc[mf][nf][i] + Res[addr];
      }
}

// ---------------------------------------------------------------------------
// Local 7x7 attention. Block = 256 thr (4 waves) = one (b,h) 8x8 tile.
// 4 lanes per pixel split the 49 neighbors (n % 4 == lane>>4).
// f16 data; MACs promote f16->f32 (compiler emits v_fma_mix_f32).
// ---------------------------------------------------------------------------
__device__ __forceinline__ void dot8(float& d, uint4 r, const float* qf) {
  const f16x8 h = __builtin_bit_cast(f16x8, r);
#pragma unroll
  for (int j = 0; j < 8; ++j) d += (float)h[j] * qf[j];
}
__device__ __forceinline__ void pv8(float* of, uint4 r, float e) {
  const f16x8 h = __builtin_bit_cast(f16x8, r);
#pragma unroll
  for (int j = 0; j < 8; ++j) of[j] += e * (float)h[j];
}

__global__ __launch_bounds__(256) void attn2_kernel(
    const u16* __restrict__ qbf, const u16* __restrict__ kpad,
    const u16* __restrict__ vpad, u16* __restrict__ att) {
  __shared__ __align__(16) u16 ks_[196 * 40];
  __shared__ __align__(16) u16 vs_[196 * 40];
  const int t = threadIdx.x;
  const int tile = blockIdx.x, bh = blockIdx.y;
  const int byy = tile / 6, bxx = tile % 6;
  const int b = bh >> 3, h = bh & 7;
  const int l = t & 63, w = t >> 6;
  const int pi = w * 16 + (l & 15);
  const int ty = pi >> 3, tx = pi & 7;
  const int ng = l >> 4;
  const int gp = (byy * 8 + ty) * kW + (bxx * 8 + tx);

  const size_t qbase = ((size_t)(b * kHW + gp)) * kC + h * 32;
  float qf[32];
#pragma unroll
  for (int c8 = 0; c8 < 4; ++c8) {
    const uint4 qq = *(const uint4*)&qbf[qbase + c8 * 8];
    const f16x8 hh = __builtin_bit_cast(f16x8, qq);
#pragma unroll
    for (int j = 0; j < 8; ++j) qf[c8 * 8 + j] = (float)hh[j];
  }

  const size_t kvbase = (size_t)bh * kPP * 32;
  for (int task = t; task < 1568; task += 256) {
    const int mat = task >= 784;
    const int rem = task - mat * 784;
    const int hp = rem >> 2, ch = rem & 3;
    const int hy = hp / 14, hx = hp - hy * 14;
    const size_t src =
        kvbase + ((size_t)((byy * 8 + hy) * kPW + (bxx * 8 + hx))) * 32 +
        ch * 8;
    const uint4 val = *(const uint4*)&(mat ? vpad : kpad)[src];
    u16* dst = mat ? vs_ : ks_;
    *(uint4*)&dst[hp * 40 + ch * 8] = val;
  }
  __syncthreads();

  float s[13];
  float pm = -1e30f;
#pragma unroll
  for (int nn = 0; nn < 13; ++nn) {
    const int n = nn * 4 + ng;
    float sc = -1e30f;
    if (n < 49) {
      const int ky = n / 7, kx = n - ky * 7;
      const int pp = (ty + ky) * 14 + (tx + kx);
      const u16* kr = &ks_[pp * 40];
      float d = 0.f;
      dot8(d, *(const uint4*)&kr[0], qf + 0);
      dot8(d, *(const uint4*)&kr[8], qf + 8);
      dot8(d, *(const uint4*)&kr[16], qf + 16);
      dot8(d, *(const uint4*)&kr[24], qf + 24);
      sc = d * kInvTemp;
    }
    s[nn] = sc;
    pm = fmaxf(pm, sc);
  }
  pm = fmaxf(pm, __shfl_xor(pm, 16));
  pm = fmaxf(pm, __shfl_xor(pm, 32));
  float zs = 0.f;
#pragma unroll
  for (int nn = 0; nn < 13; ++nn) {
    const float e = __expf(s[nn] - pm);  // masked lanes: exp(-huge) = 0
    s[nn] = e;
    zs += e;
  }
  zs += __shfl_xor(zs, 16);
  zs += __shfl_xor(zs, 32);
  const float rinv = 1.0f / zs;

  float of[32];
#pragma unroll
  for (int d = 0; d < 32; ++d) of[d] = 0.f;
#pragma unroll
  for (int nn = 0; nn < 13; ++nn) {
    const int n = nn * 4 + ng;
    if (n < 49) {
      const int ky = n / 7, kx = n - ky * 7;
      const int pp = (ty + ky) * 14 + (tx + kx);
      const u16* vr = &vs_[pp * 40];
      const float e = s[nn];
      pv8(of + 0, *(const uint4*)&vr[0], e);
      pv8(of + 8, *(const uint4*)&vr[8], e);
      pv8(of + 16, *(const uint4*)&vr[16], e);
      pv8(of + 24, *(const uint4*)&vr[24], e);
    }
  }
#pragma unroll
  for (int d = 0; d < 32; ++d) {
    of[d] += __shfl_xor(of[d], 16);
    of[d] += __shfl_xor(of[d], 32);
  }
  float seg[8];
#pragma unroll
  for (int j = 0; j < 8; ++j) {
    const float a01 = (ng == 0) ? of[j] : of[8 + j];
    const float a23 = (ng == 2) ? of[16 + j] : of[24 + j];
    seg[j] = (ng < 2) ? a01 : a23;
  }
  uint4 outv;
  outv.x = pack2h(seg[0] * rinv, seg[1] * rinv);
  outv.y = pack2h(seg[2] * rinv, seg[3] * rinv);
  outv.z = pack2h(seg[4] * rinv, seg[5] * rinv);
  outv.w = pack2h(seg[6] * rinv, seg[7] * rinv);
  *(uint4*)&att[((size_t)(b * kHW + gp)) * kC + h * 32 + ng * 8] = outv;
}

}  // namespace

extern "C" void kernel_launch(void* const* d_in, const int* in_sizes, int n_in,
                              void* d_out, int out_size, void* d_ws,
                              size_t ws_size, hipStream_t stream) {
  const float* q = (const float*)d_in[0];
  const float* k = (const float*)d_in[1];
  const float* v = (const float*)d_in[2];
  const float* Wq = (const float*)d_in[3];
  const float* Wk = (const float*)d_in[4];
  const float* Wv = (const float*)d_in[5];
  const float* Wfc = (const float*)d_in[6];
  float* out = (float*)d_out;

  u16* ws16 = (u16*)d_ws;
  u16* kpad = ws16;
  u16* vpad = ws16 + KPAD_U16;
  u16* qbf = ws16 + 2 * KPAD_U16;
  u16* att = qbf + QBF_U16;

  gemm_qkv_kernel<<<dim3(kM / 64, kC / 64, 3), 256, 0, stream>>>(
      q, k, v, Wq, Wk, Wv, qbf, kpad, vpad);

  attn2_kernel<<<dim3(36, 16), 256, 0, stream>>>(qbf, kpad, vpad, att);

  gemm_fc_kernel<<<dim3(kM / 64, kC / 64), 256, 0, stream>>>(att, Wfc, q, out);
}